// Round 12
// baseline (512.824 us; speedup 1.0000x reference)
//
#include <hip/hip_runtime.h>
#include <hip/hip_bf16.h>

#define BN_EPS 1e-5f

using short8 = __attribute__((ext_vector_type(8))) short;
using f32x4  = __attribute__((ext_vector_type(4))) float;

// 32-bit packed histogram: cnt in [31:25], fixed-point ew-sum (2^-18) in [24:0].
#define FIX_SCALE 262144.0f
#define FIX_MASK  0x01ffffffu
#define CNT_ONE   (1u << 25)

static __device__ __forceinline__ unsigned short f2bf(float f) {
  unsigned int u = __float_as_uint(f);
  unsigned int r = (u + 0x7fffu + ((u >> 16) & 1u)) >> 16;
  return (unsigned short)r;
}
static __device__ __forceinline__ float bflo(unsigned int u) { return __uint_as_float(u << 16); }
static __device__ __forceinline__ float bfhi(unsigned int u) { return __uint_as_float(u & 0xffff0000u); }

// ------------------------------------------------- weight cast (bf16, n-major)

static __global__ void cast_weights(const float* __restrict__ W1, const float* __restrict__ Wres,
                                    const float* __restrict__ W2,
                                    unsigned short* __restrict__ BT1,
                                    unsigned short* __restrict__ BT2) {
  int i = blockIdx.x * blockDim.x + threadIdx.x;
  if (i < 256 * 256) {
    int n = i >> 8, k = i & 255;
    float v = (n < 128) ? W1[k * 128 + n] : Wres[k * 128 + (n - 128)];
    BT1[i] = f2bf(v);
  } else if (i < 256 * 256 + 128 * 128) {
    int j = i - 256 * 256;
    int n = j >> 7, k = j & 127;
    BT2[j] = f2bf(W2[k * 128 + n]);
  }
}

// ---------------------------------------------------------------- fused GEMM1 + hist
// (R11 structure — best measured.)

static __global__ __launch_bounds__(256)
void fused_gemm1_hist(const float* __restrict__ A, const unsigned short* __restrict__ BT,
                      unsigned short* __restrict__ C0, unsigned short* __restrict__ C1, int M,
                      const int* __restrict__ col, const float* __restrict__ ew,
                      unsigned int* __restrict__ packed,
                      unsigned short* __restrict__ rank, int E, int gB) {
  __shared__ unsigned short As[64 * 40];
  __shared__ unsigned short Bs[256 * 40];

  int b = blockIdx.x;
  if (b >= gB) {
    int e = (b - gB) * blockDim.x + threadIdx.x;
    if (e < E) {
      int c = col[e];
      unsigned int fx = (unsigned int)(ew[e] * FIX_SCALE + 0.5f);
      unsigned int old = atomicAdd(&packed[c], CNT_ONE | fx);
      rank[e] = (unsigned short)(old >> 25);
    }
    return;
  }

  int t = threadIdx.x;
  int wv = t >> 6, lane = t & 63;
  int quad = lane >> 4, l15 = lane & 15;
  int m0 = b * 64;

  f32x4 acc[4][4];
#pragma unroll
  for (int i = 0; i < 4; ++i)
#pragma unroll
    for (int j = 0; j < 4; ++j) acc[i][j] = (f32x4){0.f, 0.f, 0.f, 0.f};

  int ar = t >> 2;
  int ac = (t & 3) * 8;
  bool avalid = (m0 + ar) < M;
  const float* Arow = A + (size_t)(m0 + ar) * 256 + ac;
  const unsigned short* Brow = BT + (size_t)t * 256;

  float4 a0 = make_float4(0.f, 0.f, 0.f, 0.f), a1 = a0;
  if (avalid) {
    a0 = *(const float4*)(Arow + 0);
    a1 = *(const float4*)(Arow + 4);
  }
  short8 b0 = *(const short8*)(Brow + 0);
  short8 b1 = *(const short8*)(Brow + 8);
  short8 b2 = *(const short8*)(Brow + 16);
  short8 b3 = *(const short8*)(Brow + 24);

  for (int k0 = 0; k0 < 256; k0 += 32) {
    short8 av;
    av[0] = (short)f2bf(a0.x); av[1] = (short)f2bf(a0.y);
    av[2] = (short)f2bf(a0.z); av[3] = (short)f2bf(a0.w);
    av[4] = (short)f2bf(a1.x); av[5] = (short)f2bf(a1.y);
    av[6] = (short)f2bf(a1.z); av[7] = (short)f2bf(a1.w);
    *(short8*)&As[ar * 40 + ac] = av;
    *(short8*)&Bs[t * 40 + 0]  = b0;
    *(short8*)&Bs[t * 40 + 8]  = b1;
    *(short8*)&Bs[t * 40 + 16] = b2;
    *(short8*)&Bs[t * 40 + 24] = b3;
    __syncthreads();

    if (k0 + 32 < 256) {
      int kn = k0 + 32;
      if (avalid) {
        a0 = *(const float4*)(Arow + kn);
        a1 = *(const float4*)(Arow + kn + 4);
      }
      b0 = *(const short8*)(Brow + kn);
      b1 = *(const short8*)(Brow + kn + 8);
      b2 = *(const short8*)(Brow + kn + 16);
      b3 = *(const short8*)(Brow + kn + 24);
    }

    short8 af[4], bf[4];
#pragma unroll
    for (int mt = 0; mt < 4; ++mt)
      af[mt] = *(const short8*)&As[(mt * 16 + l15) * 40 + quad * 8];
#pragma unroll
    for (int nt = 0; nt < 4; ++nt)
      bf[nt] = *(const short8*)&Bs[(wv * 64 + nt * 16 + l15) * 40 + quad * 8];
#pragma unroll
    for (int mt = 0; mt < 4; ++mt)
#pragma unroll
      for (int nt = 0; nt < 4; ++nt)
        acc[mt][nt] = __builtin_amdgcn_mfma_f32_16x16x32_bf16(af[mt], bf[nt], acc[mt][nt], 0, 0, 0);
    __syncthreads();
  }

  int nbase = wv * 64;
#pragma unroll
  for (int mt = 0; mt < 4; ++mt) {
#pragma unroll
    for (int nt = 0; nt < 4; ++nt) {
      int n = nbase + nt * 16 + l15;
#pragma unroll
      for (int reg = 0; reg < 4; ++reg) {
        size_t m = (size_t)(m0 + mt * 16 + quad * 4 + reg);
        if (nbase < 128) C0[m * 128 + n] = f2bf(acc[mt][nt][reg]);
        else             C1[m * 128 + (n - 128)] = f2bf(acc[mt][nt][reg]);
      }
    }
  }
}

// ---------------------------------------------------------------- scan (unpack folded in)

#define SCAN_B 256
#define SCAN_I 4
static __global__ void scanA(const unsigned int* __restrict__ packed,
                             float* __restrict__ dis, int* __restrict__ cnt,
                             int* __restrict__ start, int* __restrict__ blkSum, int N) {
  __shared__ int sh[SCAN_B];
  int t = threadIdx.x;
  int base = blockIdx.x * SCAN_B * SCAN_I + t * SCAN_I;
  int v[SCAN_I];
  int tot = 0;
#pragma unroll
  for (int j = 0; j < SCAN_I; ++j) {
    if (base + j < N) {
      unsigned int pv = packed[base + j];
      v[j] = (int)(pv >> 25);
      cnt[base + j] = v[j];
      float deg = 1.0f + (float)(pv & FIX_MASK) * (1.0f / FIX_SCALE);
      dis[base + j] = rsqrtf(deg);
    } else v[j] = 0;
    tot += v[j];
  }
  sh[t] = tot;
  __syncthreads();
  int self = tot;
  for (int off = 1; off < SCAN_B; off <<= 1) {
    int add = (t >= off) ? sh[t - off] : 0;
    __syncthreads();
    sh[t] += add;
    __syncthreads();
  }
  int excl = sh[t] - self;
  if (t == SCAN_B - 1) blkSum[blockIdx.x] = sh[t];
  int run = excl;
#pragma unroll
  for (int j = 0; j < SCAN_I; ++j) {
    if (base + j < N) start[base + j] = run;
    run += v[j];
  }
}

static __global__ void scanB(const int* __restrict__ blkSum, int* __restrict__ blkOff, int nb) {
  __shared__ int sh[256];
  int t = threadIdx.x;
  int v = (t < nb) ? blkSum[t] : 0;
  sh[t] = v;
  __syncthreads();
  for (int off = 1; off < 256; off <<= 1) {
    int add = (t >= off) ? sh[t - off] : 0;
    __syncthreads();
    sh[t] += add;
    __syncthreads();
  }
  if (t < nb) blkOff[t] = sh[t] - v;
}

static __global__ void scanC(int* start, const int* __restrict__ blkOff, int N) {
  int i = blockIdx.x * blockDim.x + threadIdx.x;
  if (i < N) start[i] += blkOff[i / (SCAN_B * SCAN_I)];
}

// atomic-free placement: pos = start[col] + rank. edges[pos] = (src, dis[src]*ew)
static __global__ void place_kernel(const int* __restrict__ row, const int* __restrict__ col,
                                    const float* __restrict__ ew, const float* __restrict__ dis,
                                    const int* __restrict__ start,
                                    const unsigned short* __restrict__ rank,
                                    long long* __restrict__ edges, int E) {
  int e = blockIdx.x * blockDim.x + threadIdx.x;
  if (e < E) {
    int r = row[e], c = col[e];
    int pos = start[c] + (int)rank[e];
    float nrm = dis[r] * ew[e];
    long long v = ((long long)__float_as_int(nrm) << 32) | (unsigned int)r;
    __builtin_nontemporal_store(v, &edges[pos]);
  }
}

// ---------------------------------------------------------------- GEMM2 (LDS-staged MFMA)

static __global__ __launch_bounds__(256)
void gemm2_mfma(const unsigned short* __restrict__ A, const unsigned short* __restrict__ BT,
                unsigned short* __restrict__ C) {
  __shared__ unsigned short As[128 * 40];
  __shared__ unsigned short Bs[128 * 40];
  int t = threadIdx.x;
  int wv = t >> 6, lane = t & 63;
  int quad = lane >> 4, l15 = lane & 15;
  int m0 = blockIdx.x * 128;

  f32x4 acc[4][4];
#pragma unroll
  for (int i = 0; i < 4; ++i)
#pragma unroll
    for (int j = 0; j < 4; ++j) acc[i][j] = (f32x4){0.f, 0.f, 0.f, 0.f};

  int sr = t >> 1, sc = (t & 1) * 16;

  for (int k0 = 0; k0 < 128; k0 += 32) {
    short8 a0 = *(const short8*)(A + (size_t)(m0 + sr) * 128 + k0 + sc);
    short8 a1 = *(const short8*)(A + (size_t)(m0 + sr) * 128 + k0 + sc + 8);
    *(short8*)&As[sr * 40 + sc]     = a0;
    *(short8*)&As[sr * 40 + sc + 8] = a1;
    short8 b0 = *(const short8*)(BT + (size_t)sr * 128 + k0 + sc);
    short8 b1 = *(const short8*)(BT + (size_t)sr * 128 + k0 + sc + 8);
    *(short8*)&Bs[sr * 40 + sc]     = b0;
    *(short8*)&Bs[sr * 40 + sc + 8] = b1;
    __syncthreads();

    int mb = (wv >> 1) * 64, nb = (wv & 1) * 64;
    short8 af[4], bf[4];
#pragma unroll
    for (int mt = 0; mt < 4; ++mt)
      af[mt] = *(const short8*)&As[(mb + mt * 16 + l15) * 40 + quad * 8];
#pragma unroll
    for (int nt = 0; nt < 4; ++nt)
      bf[nt] = *(const short8*)&Bs[(nb + nt * 16 + l15) * 40 + quad * 8];
#pragma unroll
    for (int mt = 0; mt < 4; ++mt)
#pragma unroll
      for (int nt = 0; nt < 4; ++nt)
        acc[mt][nt] = __builtin_amdgcn_mfma_f32_16x16x32_bf16(af[mt], bf[nt], acc[mt][nt], 0, 0, 0);
    __syncthreads();
  }

  int mb = (wv >> 1) * 64, nb = (wv & 1) * 64;
#pragma unroll
  for (int mt = 0; mt < 4; ++mt)
#pragma unroll
    for (int nt = 0; nt < 4; ++nt) {
      int n = nb + nt * 16 + l15;
#pragma unroll
      for (int reg = 0; reg < 4; ++reg) {
        size_t m = (size_t)(m0 + mb + mt * 16 + quad * 4 + reg);
        C[m * 128 + n] = f2bf(acc[mt][nt][reg]);
      }
    }
}

// ---------------------------------------------------------------- propagation (wide-gather)
// One wave per destination node. lane = g*16+c (g in [0,4), c in [0,16)).
// Per 16-edge step each lane issues FOUR independent uint4 (16 B) gathers —
// 4 source rows per instruction at the 16 B/lane coalescing sweet spot
// (vs 4 B/lane before: 4x fewer VMEM instructions, same MLP depth).
// Lane accumulates channels c*8..c*8+7; 2-step shfl_xor(16,32) butterfly
// folds the 4 g-partials; epilogue on g==0 lanes.

#define PROP_WIDE_GATHER                                                        \
  int g = lane >> 4, c = lane & 15;                                             \
  float acc[8];                                                                 \
  _Pragma("unroll") for (int i = 0; i < 8; ++i) acc[i] = 0.f;                   \
  int s = start[w], n = cnt[w];                                                 \
  int k = 0;                                                                    \
  while (k < n) {                                                               \
    int chunk = min(n - k, 64);                                                 \
    int idx = 0;                                                                \
    float wt = 0.f;                                                             \
    if (lane < chunk) {                                                         \
      long long ev = edges[s + k + lane];                                       \
      idx = (int)(unsigned int)(ev & 0xffffffffLL);                             \
      wt  = __int_as_float((int)(ev >> 32));                                    \
    }                                                                           \
    for (int j = 0; j < chunk; j += 16) {                                       \
      int   i0 = __shfl(idx, j + g, 64);       float w0 = __shfl(wt, j + g, 64);\
      int   i1 = __shfl(idx, j + 4 + g, 64);   float w1 = __shfl(wt, j + 4 + g, 64);\
      int   i2 = __shfl(idx, j + 8 + g, 64);   float w2 = __shfl(wt, j + 8 + g, 64);\
      int   i3 = __shfl(idx, j + 12 + g, 64);  float w3 = __shfl(wt, j + 12 + g, 64);\
      uint4 u0 = *(const uint4*)(Hsrc + (size_t)i0 * 64 + c * 4);               \
      uint4 u1 = *(const uint4*)(Hsrc + (size_t)i1 * 64 + c * 4);               \
      uint4 u2 = *(const uint4*)(Hsrc + (size_t)i2 * 64 + c * 4);               \
      uint4 u3 = *(const uint4*)(Hsrc + (size_t)i3 * 64 + c * 4);               \
      acc[0] = fmaf(w0, bflo(u0.x), acc[0]); acc[1] = fmaf(w0, bfhi(u0.x), acc[1]);\
      acc[2] = fmaf(w0, bflo(u0.y), acc[2]); acc[3] = fmaf(w0, bfhi(u0.y), acc[3]);\
      acc[4] = fmaf(w0, bflo(u0.z), acc[4]); acc[5] = fmaf(w0, bfhi(u0.z), acc[5]);\
      acc[6] = fmaf(w0, bflo(u0.w), acc[6]); acc[7] = fmaf(w0, bfhi(u0.w), acc[7]);\
      acc[0] = fmaf(w1, bflo(u1.x), acc[0]); acc[1] = fmaf(w1, bfhi(u1.x), acc[1]);\
      acc[2] = fmaf(w1, bflo(u1.y), acc[2]); acc[3] = fmaf(w1, bfhi(u1.y), acc[3]);\
      acc[4] = fmaf(w1, bflo(u1.z), acc[4]); acc[5] = fmaf(w1, bfhi(u1.z), acc[5]);\
      acc[6] = fmaf(w1, bflo(u1.w), acc[6]); acc[7] = fmaf(w1, bfhi(u1.w), acc[7]);\
      acc[0] = fmaf(w2, bflo(u2.x), acc[0]); acc[1] = fmaf(w2, bfhi(u2.x), acc[1]);\
      acc[2] = fmaf(w2, bflo(u2.y), acc[2]); acc[3] = fmaf(w2, bfhi(u2.y), acc[3]);\
      acc[4] = fmaf(w2, bflo(u2.z), acc[4]); acc[5] = fmaf(w2, bfhi(u2.z), acc[5]);\
      acc[6] = fmaf(w2, bflo(u2.w), acc[6]); acc[7] = fmaf(w2, bfhi(u2.w), acc[7]);\
      acc[0] = fmaf(w3, bflo(u3.x), acc[0]); acc[1] = fmaf(w3, bfhi(u3.x), acc[1]);\
      acc[2] = fmaf(w3, bflo(u3.y), acc[2]); acc[3] = fmaf(w3, bfhi(u3.y), acc[3]);\
      acc[4] = fmaf(w3, bflo(u3.z), acc[4]); acc[5] = fmaf(w3, bfhi(u3.z), acc[5]);\
      acc[6] = fmaf(w3, bflo(u3.w), acc[6]); acc[7] = fmaf(w3, bfhi(u3.w), acc[7]);\
    }                                                                           \
    k += chunk;                                                                 \
  }                                                                             \
  _Pragma("unroll") for (int i = 0; i < 8; ++i) {                               \
    acc[i] += __shfl_xor(acc[i], 16, 64);                                       \
    acc[i] += __shfl_xor(acc[i], 32, 64);                                       \
  }

// prop1: h1 = relu(bn1(agg + b1)) -> bf16 packed (uint4 row of 16)
static __global__ __launch_bounds__(256)
void prop128_bf16out(const unsigned int* __restrict__ Hsrc,
                     const int* __restrict__ start, const int* __restrict__ cnt,
                     const long long* __restrict__ edges,
                     const float* __restrict__ dis,
                     const float* __restrict__ bvec,
                     const float* __restrict__ gam, const float* __restrict__ be,
                     const float* __restrict__ mean, const float* __restrict__ var,
                     uint4* __restrict__ Outb, int N) {
  int w = (int)((blockIdx.x * blockDim.x + threadIdx.x) >> 6);
  int lane = threadIdx.x & 63;
  if (w >= N) return;
  PROP_WIDE_GATHER
  if (g == 0) {
    float d = dis[w];
    uint4 hv = *(const uint4*)(Hsrc + (size_t)w * 64 + c * 4);
    float hs[8] = {bflo(hv.x), bfhi(hv.x), bflo(hv.y), bfhi(hv.y),
                   bflo(hv.z), bfhi(hv.z), bflo(hv.w), bfhi(hv.w)};
    int ch = c * 8;
    unsigned int ow[4];
#pragma unroll
    for (int h = 0; h < 4; ++h) {
      float v0, v1;
#pragma unroll
      for (int q = 0; q < 2; ++q) {
        int i = h * 2 + q;
        float v = d * (d * hs[i] + acc[i]) + bvec[ch + i];
        float sc = gam[ch + i] * rsqrtf(var[ch + i] + BN_EPS);
        v = fmaxf((v - mean[ch + i]) * sc + be[ch + i], 0.f);
        if (q == 0) v0 = v; else v1 = v;
      }
      ow[h] = (unsigned int)f2bf(v0) | ((unsigned int)f2bf(v1) << 16);
    }
    uint4 o; o.x = ow[0]; o.y = ow[1]; o.z = ow[2]; o.w = ow[3];
    Outb[(size_t)w * 16 + c] = o;
  }
}

// prop2: h2 = relu(bn2(agg + b2 + res)); fused h3[w] = dot(h2_row, W3).
static __global__ __launch_bounds__(256)
void prop128_w3out(const unsigned int* __restrict__ Hsrc,
                   const int* __restrict__ start, const int* __restrict__ cnt,
                   const long long* __restrict__ edges,
                   const float* __restrict__ dis,
                   const float* __restrict__ bvec,
                   const float* __restrict__ gam, const float* __restrict__ be,
                   const float* __restrict__ mean, const float* __restrict__ var,
                   const uint4* __restrict__ resb, const float* __restrict__ W3,
                   float* __restrict__ h3, int N) {
  int w = (int)((blockIdx.x * blockDim.x + threadIdx.x) >> 6);
  int lane = threadIdx.x & 63;
  if (w >= N) return;
  PROP_WIDE_GATHER
  if (g == 0) {
    float d = dis[w];
    uint4 hv = *(const uint4*)(Hsrc + (size_t)w * 64 + c * 4);
    uint4 rv = resb[(size_t)w * 16 + c];
    float hs[8] = {bflo(hv.x), bfhi(hv.x), bflo(hv.y), bfhi(hv.y),
                   bflo(hv.z), bfhi(hv.z), bflo(hv.w), bfhi(hv.w)};
    float rs[8] = {bflo(rv.x), bfhi(rv.x), bflo(rv.y), bfhi(rv.y),
                   bflo(rv.z), bfhi(rv.z), bflo(rv.w), bfhi(rv.w)};
    int ch = c * 8;
    float part = 0.f;
#pragma unroll
    for (int i = 0; i < 8; ++i) {
      float v = d * (d * hs[i] + acc[i]) + bvec[ch + i] + rs[i];
      float sc = gam[ch + i] * rsqrtf(var[ch + i] + BN_EPS);
      v = fmaxf((v - mean[ch + i]) * sc + be[ch + i], 0.f);
      part = fmaf(v, W3[ch + i], part);
    }
    part += __shfl_xor(part, 1, 64);
    part += __shfl_xor(part, 2, 64);
    part += __shfl_xor(part, 4, 64);
    part += __shfl_xor(part, 8, 64);
    if (c == 0) h3[w] = part;
  }
}

// ---------------------------------------------------------------- final 1-wide propagation

static __global__ void prop3_kernel(const float* __restrict__ h3,
                                    const int* __restrict__ start, const int* __restrict__ cnt,
                                    const long long* __restrict__ edges,
                                    const float* __restrict__ dis, const float* __restrict__ b3,
                                    float* __restrict__ out, int N) {
  int i = blockIdx.x * blockDim.x + threadIdx.x;
  if (i >= N) return;
  float d = dis[i];
  float acc = d * h3[i];
  int s = start[i], n = cnt[i];
  for (int k = 0; k < n; ++k) {
    long long ev = edges[s + k];
    int src = (int)(unsigned int)(ev & 0xffffffffLL);
    float wt = __int_as_float((int)(ev >> 32));
    acc = fmaf(wt, h3[src], acc);
  }
  out[i] = acc * d + b3[0];
}

// ---------------------------------------------------------------- launch

extern "C" void kernel_launch(void* const* d_in, const int* in_sizes, int n_in,
                              void* d_out, int out_size, void* d_ws, size_t ws_size,
                              hipStream_t stream) {
  const float* x    = (const float*)d_in[0];
  const int*   ei   = (const int*)d_in[1];
  const float* ew   = (const float*)d_in[2];
  const float* W1   = (const float*)d_in[3];
  const float* b1   = (const float*)d_in[4];
  const float* W2   = (const float*)d_in[5];
  const float* b2   = (const float*)d_in[6];
  const float* W3   = (const float*)d_in[7];
  const float* b3   = (const float*)d_in[8];
  const float* Wres = (const float*)d_in[9];
  const float* g1   = (const float*)d_in[10];
  const float* be1  = (const float*)d_in[11];
  const float* m1   = (const float*)d_in[12];
  const float* v1   = (const float*)d_in[13];
  const float* g2   = (const float*)d_in[14];
  const float* be2  = (const float*)d_in[15];
  const float* m2   = (const float*)d_in[16];
  const float* v2   = (const float*)d_in[17];

  int Hh = in_sizes[4];            // 128
  int V  = in_sizes[3] / Hh;       // 256
  int N  = in_sizes[0] / V;        // 100000
  int E  = in_sizes[2];            // 1600000
  const int* row = ei;
  const int* col = ei + E;

  int Mp = ((N + 127) / 128) * 128;

  char* p = (char*)d_ws;
  auto alloc = [&](size_t bytes) -> char* {
    char* r = p;
    p += (bytes + 255) & ~(size_t)255;
    return r;
  };
  unsigned int* packed = (unsigned int*)alloc((size_t)N * 4);
  float* dis    = (float*)alloc((size_t)N * 4);
  int*   cnt    = (int*)  alloc((size_t)N * 4);
  int*   startA = (int*)  alloc((size_t)N * 4);
  int*   blkSum = (int*)  alloc(256 * 4);
  int*   blkOff = (int*)  alloc(256 * 4);
  unsigned short* rank = (unsigned short*)alloc((size_t)E * 2);
  long long* edges = (long long*)alloc((size_t)E * 8);
  float* h3     = (float*)alloc((size_t)N * 4);
  unsigned short* BT1 = (unsigned short*)alloc((size_t)256 * 256 * 2);
  unsigned short* BT2 = (unsigned short*)alloc((size_t)128 * 128 * 2);
  unsigned short* bufG  = (unsigned short*)alloc((size_t)Mp * 128 * 2);  // h0, then h1W2 (bf16)
  unsigned short* bufH1 = (unsigned short*)alloc((size_t)Mp * 128 * 2);  // h1 bf16
  unsigned short* bufRes = (unsigned short*)alloc((size_t)Mp * 128 * 2); // x@Wres bf16
  (void)ws_size; (void)n_in; (void)out_size;

  int TB = 256;
  hipMemsetAsync(packed, 0, (size_t)N * 4, stream);
  cast_weights<<<(256 * 256 + 128 * 128 + TB - 1) / TB, TB, 0, stream>>>(W1, Wres, W2, BT1, BT2);

  // fused: GEMM1 (blocks [0,gB)) + hist (blocks [gB, gB+hB))
  int gB = Mp / 64;
  int hB = (E + TB - 1) / TB;
  fused_gemm1_hist<<<gB + hB, TB, 0, stream>>>(x, BT1, bufG, bufRes, N,
                                               col, ew, packed, rank, E, gB);

  int nb = (N + SCAN_B * SCAN_I - 1) / (SCAN_B * SCAN_I);
  scanA<<<nb, SCAN_B, 0, stream>>>(packed, dis, cnt, startA, blkSum, N);
  scanB<<<1, 256, 0, stream>>>(blkSum, blkOff, nb);
  scanC<<<(N + TB - 1) / TB, TB, 0, stream>>>(startA, blkOff, N);
  place_kernel<<<(E + TB - 1) / TB, TB, 0, stream>>>(row, col, ew, dis, startA,
                                                     rank, edges, E);

  // prop1: h1 = relu(bn1(agg(h0) + b1)) -> bufH1 (bf16)
  int propBlocks = (int)(((size_t)N * 64 + TB - 1) / TB);
  prop128_bf16out<<<propBlocks, TB, 0, stream>>>((const unsigned int*)bufG, startA, cnt,
                                                 edges, dis, b1, g1, be1, m1, v1,
                                                 (uint4*)bufH1, N);

  // GEMM2: h1 @ W2 -> bufG (bf16, reused)
  gemm2_mfma<<<Mp / 128, 256, 0, stream>>>(bufH1, BT2, bufG);

  // prop2 + fused W3: h3 = relu(bn2(agg(h1W2) + b2 + res)) . W3
  prop128_w3out<<<propBlocks, TB, 0, stream>>>((const unsigned int*)bufG, startA, cnt,
                                               edges, dis, b2, g2, be2, m2, v2,
                                               (const uint4*)bufRes, W3, h3, N);

  // out = agg(h3) + b3
  prop3_kernel<<<(N + TB - 1) / TB, TB, 0, stream>>>(h3, startA, cnt, edges,
                                                     dis, b3, (float*)d_out, N);
}

// Round 13
// 507.160 us; speedup vs baseline: 1.0112x; 1.0112x over previous
//
#include <hip/hip_runtime.h>
#include <hip/hip_bf16.h>

#define BN_EPS 1e-5f

using short8 = __attribute__((ext_vector_type(8))) short;
using f32x4  = __attribute__((ext_vector_type(4))) float;

// 32-bit packed histogram: cnt in [31:25], fixed-point ew-sum (2^-18) in [24:0].
#define FIX_SCALE 262144.0f
#define FIX_MASK  0x01ffffffu
#define CNT_ONE   (1u << 25)

static __device__ __forceinline__ unsigned short f2bf(float f) {
  unsigned int u = __float_as_uint(f);
  unsigned int r = (u + 0x7fffu + ((u >> 16) & 1u)) >> 16;
  return (unsigned short)r;
}

// ------------------------------------------------- weight cast (bf16, n-major)

static __global__ void cast_weights(const float* __restrict__ W1, const float* __restrict__ Wres,
                                    const float* __restrict__ W2,
                                    unsigned short* __restrict__ BT1,
                                    unsigned short* __restrict__ BT2) {
  int i = blockIdx.x * blockDim.x + threadIdx.x;
  if (i < 256 * 256) {
    int n = i >> 8, k = i & 255;
    float v = (n < 128) ? W1[k * 128 + n] : Wres[k * 128 + (n - 128)];
    BT1[i] = f2bf(v);
  } else if (i < 256 * 256 + 128 * 128) {
    int j = i - 256 * 256;
    int n = j >> 7, k = j & 127;
    BT2[j] = f2bf(W2[k * 128 + n]);
  }
}

// ---------------------------------------------------------------- fused hist + GEMM1
// HIST FIRST (blocks [0,hB)), gemm after (blocks [hB,hB+gB)).
// Rationale (R11 post-mortem): in-order dispatch + long-lived gemm blocks first
// = zero overlap (fused ~ gemm+hist serial). Hist blocks are SHORT (4
// wave-atomics each) so with hist first they retire continuously; gemm blocks
// stream in within ~µs and run concurrently with the atomic-bound hist tail —
// MFMA/LDS pipe overlaps the atomic pipe for most of the window.
// GEMM1: LDS-staged MFMA with register-prefetch pipeline (R11).

static __global__ __launch_bounds__(256)
void fused_hist_gemm1(const float* __restrict__ A, const unsigned short* __restrict__ BT,
                      unsigned short* __restrict__ C0, unsigned short* __restrict__ C1, int M,
                      const int* __restrict__ col, const float* __restrict__ ew,
                      unsigned int* __restrict__ packed,
                      unsigned short* __restrict__ rank, int E, int hB) {
  __shared__ unsigned short As[64 * 40];
  __shared__ unsigned short Bs[256 * 40];

  int b = blockIdx.x;
  if (b < hB) {
    // ---------------- hist role (atomic pipe only; short-lived)
    int e = b * blockDim.x + threadIdx.x;
    if (e < E) {
      int c = col[e];
      unsigned int fx = (unsigned int)(ew[e] * FIX_SCALE + 0.5f);
      unsigned int old = atomicAdd(&packed[c], CNT_ONE | fx);
      rank[e] = (unsigned short)(old >> 25);
    }
    return;
  }

  // ---------------- gemm role
  int g = b - hB;
  int t = threadIdx.x;
  int wv = t >> 6, lane = t & 63;
  int quad = lane >> 4, l15 = lane & 15;
  int m0 = g * 64;

  f32x4 acc[4][4];
#pragma unroll
  for (int i = 0; i < 4; ++i)
#pragma unroll
    for (int j = 0; j < 4; ++j) acc[i][j] = (f32x4){0.f, 0.f, 0.f, 0.f};

  int ar = t >> 2;
  int ac = (t & 3) * 8;
  bool avalid = (m0 + ar) < M;
  const float* Arow = A + (size_t)(m0 + ar) * 256 + ac;
  const unsigned short* Brow = BT + (size_t)t * 256;

  float4 a0 = make_float4(0.f, 0.f, 0.f, 0.f), a1 = a0;
  if (avalid) {
    a0 = *(const float4*)(Arow + 0);
    a1 = *(const float4*)(Arow + 4);
  }
  short8 b0 = *(const short8*)(Brow + 0);
  short8 b1 = *(const short8*)(Brow + 8);
  short8 b2 = *(const short8*)(Brow + 16);
  short8 b3 = *(const short8*)(Brow + 24);

  for (int k0 = 0; k0 < 256; k0 += 32) {
    short8 av;
    av[0] = (short)f2bf(a0.x); av[1] = (short)f2bf(a0.y);
    av[2] = (short)f2bf(a0.z); av[3] = (short)f2bf(a0.w);
    av[4] = (short)f2bf(a1.x); av[5] = (short)f2bf(a1.y);
    av[6] = (short)f2bf(a1.z); av[7] = (short)f2bf(a1.w);
    *(short8*)&As[ar * 40 + ac] = av;
    *(short8*)&Bs[t * 40 + 0]  = b0;
    *(short8*)&Bs[t * 40 + 8]  = b1;
    *(short8*)&Bs[t * 40 + 16] = b2;
    *(short8*)&Bs[t * 40 + 24] = b3;
    __syncthreads();

    if (k0 + 32 < 256) {
      int kn = k0 + 32;
      if (avalid) {
        a0 = *(const float4*)(Arow + kn);
        a1 = *(const float4*)(Arow + kn + 4);
      }
      b0 = *(const short8*)(Brow + kn);
      b1 = *(const short8*)(Brow + kn + 8);
      b2 = *(const short8*)(Brow + kn + 16);
      b3 = *(const short8*)(Brow + kn + 24);
    }

    short8 af[4], bf[4];
#pragma unroll
    for (int mt = 0; mt < 4; ++mt)
      af[mt] = *(const short8*)&As[(mt * 16 + l15) * 40 + quad * 8];
#pragma unroll
    for (int nt = 0; nt < 4; ++nt)
      bf[nt] = *(const short8*)&Bs[(wv * 64 + nt * 16 + l15) * 40 + quad * 8];
#pragma unroll
    for (int mt = 0; mt < 4; ++mt)
#pragma unroll
      for (int nt = 0; nt < 4; ++nt)
        acc[mt][nt] = __builtin_amdgcn_mfma_f32_16x16x32_bf16(af[mt], bf[nt], acc[mt][nt], 0, 0, 0);
    __syncthreads();
  }

  int nbase = wv * 64;
#pragma unroll
  for (int mt = 0; mt < 4; ++mt) {
#pragma unroll
    for (int nt = 0; nt < 4; ++nt) {
      int n = nbase + nt * 16 + l15;
#pragma unroll
      for (int reg = 0; reg < 4; ++reg) {
        size_t m = (size_t)(m0 + mt * 16 + quad * 4 + reg);
        if (nbase < 128) C0[m * 128 + n] = f2bf(acc[mt][nt][reg]);
        else             C1[m * 128 + (n - 128)] = f2bf(acc[mt][nt][reg]);
      }
    }
  }
}

// ---------------------------------------------------------------- scan (unpack folded in)
// scanC eliminated: consumers add blkOff[i >> 10] at use time.

#define SCAN_B 256
#define SCAN_I 4
static __global__ void scanA(const unsigned int* __restrict__ packed,
                             float* __restrict__ dis, int* __restrict__ cnt,
                             int* __restrict__ start, int* __restrict__ blkSum, int N) {
  __shared__ int sh[SCAN_B];
  int t = threadIdx.x;
  int base = blockIdx.x * SCAN_B * SCAN_I + t * SCAN_I;
  int v[SCAN_I];
  int tot = 0;
#pragma unroll
  for (int j = 0; j < SCAN_I; ++j) {
    if (base + j < N) {
      unsigned int pv = packed[base + j];
      v[j] = (int)(pv >> 25);
      cnt[base + j] = v[j];
      float deg = 1.0f + (float)(pv & FIX_MASK) * (1.0f / FIX_SCALE);
      dis[base + j] = rsqrtf(deg);
    } else v[j] = 0;
    tot += v[j];
  }
  sh[t] = tot;
  __syncthreads();
  int self = tot;
  for (int off = 1; off < SCAN_B; off <<= 1) {
    int add = (t >= off) ? sh[t - off] : 0;
    __syncthreads();
    sh[t] += add;
    __syncthreads();
  }
  int excl = sh[t] - self;
  if (t == SCAN_B - 1) blkSum[blockIdx.x] = sh[t];
  int run = excl;
#pragma unroll
  for (int j = 0; j < SCAN_I; ++j) {
    if (base + j < N) start[base + j] = run;
    run += v[j];
  }
}

static __global__ void scanB(const int* __restrict__ blkSum, int* __restrict__ blkOff, int nb) {
  __shared__ int sh[256];
  int t = threadIdx.x;
  int v = (t < nb) ? blkSum[t] : 0;
  sh[t] = v;
  __syncthreads();
  for (int off = 1; off < 256; off <<= 1) {
    int add = (t >= off) ? sh[t - off] : 0;
    __syncthreads();
    sh[t] += add;
    __syncthreads();
  }
  if (t < nb) blkOff[t] = sh[t] - v;
}

// atomic-free placement: pos = start[col] + blkOff[col>>10] + rank.
static __global__ void place_kernel(const int* __restrict__ row, const int* __restrict__ col,
                                    const float* __restrict__ ew, const float* __restrict__ dis,
                                    const int* __restrict__ start,
                                    const int* __restrict__ blkOff,
                                    const unsigned short* __restrict__ rank,
                                    long long* __restrict__ edges, int E) {
  int e = blockIdx.x * blockDim.x + threadIdx.x;
  if (e < E) {
    int r = row[e], c = col[e];
    int pos = start[c] + blkOff[c >> 10] + (int)rank[e];
    float nrm = dis[r] * ew[e];
    long long v = ((long long)__float_as_int(nrm) << 32) | (unsigned int)r;
    __builtin_nontemporal_store(v, &edges[pos]);
  }
}

// ---------------------------------------------------------------- GEMM2 (LDS-staged MFMA)

static __global__ __launch_bounds__(256)
void gemm2_mfma(const unsigned short* __restrict__ A, const unsigned short* __restrict__ BT,
                unsigned short* __restrict__ C) {
  __shared__ unsigned short As[128 * 40];
  __shared__ unsigned short Bs[128 * 40];
  int t = threadIdx.x;
  int wv = t >> 6, lane = t & 63;
  int quad = lane >> 4, l15 = lane & 15;
  int m0 = blockIdx.x * 128;

  f32x4 acc[4][4];
#pragma unroll
  for (int i = 0; i < 4; ++i)
#pragma unroll
    for (int j = 0; j < 4; ++j) acc[i][j] = (f32x4){0.f, 0.f, 0.f, 0.f};

  int sr = t >> 1, sc = (t & 1) * 16;

  for (int k0 = 0; k0 < 128; k0 += 32) {
    short8 a0 = *(const short8*)(A + (size_t)(m0 + sr) * 128 + k0 + sc);
    short8 a1 = *(const short8*)(A + (size_t)(m0 + sr) * 128 + k0 + sc + 8);
    *(short8*)&As[sr * 40 + sc]     = a0;
    *(short8*)&As[sr * 40 + sc + 8] = a1;
    short8 b0 = *(const short8*)(BT + (size_t)sr * 128 + k0 + sc);
    short8 b1 = *(const short8*)(BT + (size_t)sr * 128 + k0 + sc + 8);
    *(short8*)&Bs[sr * 40 + sc]     = b0;
    *(short8*)&Bs[sr * 40 + sc + 8] = b1;
    __syncthreads();

    int mb = (wv >> 1) * 64, nb = (wv & 1) * 64;
    short8 af[4], bf[4];
#pragma unroll
    for (int mt = 0; mt < 4; ++mt)
      af[mt] = *(const short8*)&As[(mb + mt * 16 + l15) * 40 + quad * 8];
#pragma unroll
    for (int nt = 0; nt < 4; ++nt)
      bf[nt] = *(const short8*)&Bs[(nb + nt * 16 + l15) * 40 + quad * 8];
#pragma unroll
    for (int mt = 0; mt < 4; ++mt)
#pragma unroll
      for (int nt = 0; nt < 4; ++nt)
        acc[mt][nt] = __builtin_amdgcn_mfma_f32_16x16x32_bf16(af[mt], bf[nt], acc[mt][nt], 0, 0, 0);
    __syncthreads();
  }

  int mb = (wv >> 1) * 64, nb = (wv & 1) * 64;
#pragma unroll
  for (int mt = 0; mt < 4; ++mt)
#pragma unroll
    for (int nt = 0; nt < 4; ++nt) {
      int n = nb + nt * 16 + l15;
#pragma unroll
      for (int reg = 0; reg < 4; ++reg) {
        size_t m = (size_t)(m0 + mb + mt * 16 + quad * 4 + reg);
        C[m * 128 + n] = f2bf(acc[mt][nt][reg]);
      }
    }
}

// ---------------------------------------------------------------- propagation core (R11 form)
// One wave per destination node; lane holds 2 channels (one bf16x2 word).
// Uniform-index __shfl broadcasts (v_readlane) + 8 independent 4 B gathers/group.
// start folded: s = start[w] + blkOff[w>>10].

#define PROP_GATHER_BODY                                                        \
  int c0 = lane * 2;                                                            \
  float d = dis[w];                                                             \
  float acc0, acc1;                                                             \
  {                                                                             \
    unsigned int u = Hsrc[(size_t)w * 64 + lane];                               \
    acc0 = d * __uint_as_float(u << 16);                                        \
    acc1 = d * __uint_as_float(u & 0xffff0000u);                                \
  }                                                                             \
  int s = start[w] + blkOff[w >> 10], n = cnt[w];                               \
  int k = 0;                                                                    \
  while (k < n) {                                                               \
    int chunk = min(n - k, 64);                                                 \
    int idx = 0;                                                                \
    float wt = 0.f;                                                             \
    if (lane < chunk) {                                                         \
      long long ev = edges[s + k + lane];                                       \
      idx = (int)(unsigned int)(ev & 0xffffffffLL);                             \
      wt  = __int_as_float((int)(ev >> 32));                                    \
    }                                                                           \
    for (int j = 0; j < chunk; j += 8) {                                        \
      int   i0 = __shfl(idx, j + 0, 64), i1 = __shfl(idx, j + 1, 64);           \
      int   i2 = __shfl(idx, j + 2, 64), i3 = __shfl(idx, j + 3, 64);           \
      int   i4 = __shfl(idx, j + 4, 64), i5 = __shfl(idx, j + 5, 64);           \
      int   i6 = __shfl(idx, j + 6, 64), i7 = __shfl(idx, j + 7, 64);           \
      float w0 = __shfl(wt, j + 0, 64), w1 = __shfl(wt, j + 1, 64);             \
      float w2 = __shfl(wt, j + 2, 64), w3 = __shfl(wt, j + 3, 64);             \
      float w4 = __shfl(wt, j + 4, 64), w5 = __shfl(wt, j + 5, 64);             \
      float w6 = __shfl(wt, j + 6, 64), w7 = __shfl(wt, j + 7, 64);             \
      unsigned int u0 = Hsrc[(size_t)i0 * 64 + lane];                           \
      unsigned int u1 = Hsrc[(size_t)i1 * 64 + lane];                           \
      unsigned int u2 = Hsrc[(size_t)i2 * 64 + lane];                           \
      unsigned int u3 = Hsrc[(size_t)i3 * 64 + lane];                           \
      unsigned int u4 = Hsrc[(size_t)i4 * 64 + lane];                           \
      unsigned int u5 = Hsrc[(size_t)i5 * 64 + lane];                           \
      unsigned int u6 = Hsrc[(size_t)i6 * 64 + lane];                           \
      unsigned int u7 = Hsrc[(size_t)i7 * 64 + lane];                           \
      acc0 = fmaf(w0, __uint_as_float(u0 << 16), acc0);                         \
      acc1 = fmaf(w0, __uint_as_float(u0 & 0xffff0000u), acc1);                 \
      acc0 = fmaf(w1, __uint_as_float(u1 << 16), acc0);                         \
      acc1 = fmaf(w1, __uint_as_float(u1 & 0xffff0000u), acc1);                 \
      acc0 = fmaf(w2, __uint_as_float(u2 << 16), acc0);                         \
      acc1 = fmaf(w2, __uint_as_float(u2 & 0xffff0000u), acc1);                 \
      acc0 = fmaf(w3, __uint_as_float(u3 << 16), acc0);                         \
      acc1 = fmaf(w3, __uint_as_float(u3 & 0xffff0000u), acc1);                 \
      acc0 = fmaf(w4, __uint_as_float(u4 << 16), acc0);                         \
      acc1 = fmaf(w4, __uint_as_float(u4 & 0xffff0000u), acc1);                 \
      acc0 = fmaf(w5, __uint_as_float(u5 << 16), acc0);                         \
      acc1 = fmaf(w5, __uint_as_float(u5 & 0xffff0000u), acc1);                 \
      acc0 = fmaf(w6, __uint_as_float(u6 << 16), acc0);                         \
      acc1 = fmaf(w6, __uint_as_float(u6 & 0xffff0000u), acc1);                 \
      acc0 = fmaf(w7, __uint_as_float(u7 << 16), acc0);                         \
      acc1 = fmaf(w7, __uint_as_float(u7 & 0xffff0000u), acc1);                 \
    }                                                                           \
    k += chunk;                                                                 \
  }                                                                             \
  acc0 *= d;                                                                    \
  acc1 *= d;

// prop1: h1 = relu(bn1(agg + b1)) -> bf16 packed output
static __global__ __launch_bounds__(256)
void prop128_bf16out(const unsigned int* __restrict__ Hsrc,
                     const int* __restrict__ start, const int* __restrict__ blkOff,
                     const int* __restrict__ cnt,
                     const long long* __restrict__ edges,
                     const float* __restrict__ dis,
                     const float* __restrict__ bvec,
                     const float* __restrict__ g, const float* __restrict__ be,
                     const float* __restrict__ mean, const float* __restrict__ var,
                     unsigned int* __restrict__ Outb, int N) {
  int w = (int)((blockIdx.x * blockDim.x + threadIdx.x) >> 6);
  int lane = threadIdx.x & 63;
  if (w >= N) return;
  PROP_GATHER_BODY
  float x0 = acc0 + bvec[c0];
  float x1 = acc1 + bvec[c0 + 1];
  float s0 = g[c0] * rsqrtf(var[c0] + BN_EPS);
  float s1 = g[c0 + 1] * rsqrtf(var[c0 + 1] + BN_EPS);
  x0 = fmaxf((x0 - mean[c0]) * s0 + be[c0], 0.f);
  x1 = fmaxf((x1 - mean[c0 + 1]) * s1 + be[c0 + 1], 0.f);
  unsigned int packed = (unsigned int)f2bf(x0) | ((unsigned int)f2bf(x1) << 16);
  Outb[(size_t)w * 64 + lane] = packed;
}

// prop2: h2 = relu(bn2(agg + b2 + res)); fused h3[w] = dot(h2_row, W3).
static __global__ __launch_bounds__(256)
void prop128_w3out(const unsigned int* __restrict__ Hsrc,
                   const int* __restrict__ start, const int* __restrict__ blkOff,
                   const int* __restrict__ cnt,
                   const long long* __restrict__ edges,
                   const float* __restrict__ dis,
                   const float* __restrict__ bvec,
                   const float* __restrict__ g, const float* __restrict__ be,
                   const float* __restrict__ mean, const float* __restrict__ var,
                   const unsigned int* __restrict__ resb, const float* __restrict__ W3,
                   float* __restrict__ h3, int N) {
  int w = (int)((blockIdx.x * blockDim.x + threadIdx.x) >> 6);
  int lane = threadIdx.x & 63;
  if (w >= N) return;
  PROP_GATHER_BODY
  unsigned int ru = resb[(size_t)w * 64 + lane];
  float x0 = acc0 + bvec[c0]     + __uint_as_float(ru << 16);
  float x1 = acc1 + bvec[c0 + 1] + __uint_as_float(ru & 0xffff0000u);
  float s0 = g[c0] * rsqrtf(var[c0] + BN_EPS);
  float s1 = g[c0 + 1] * rsqrtf(var[c0 + 1] + BN_EPS);
  x0 = fmaxf((x0 - mean[c0]) * s0 + be[c0], 0.f);
  x1 = fmaxf((x1 - mean[c0 + 1]) * s1 + be[c0 + 1], 0.f);
  float v = x0 * W3[c0] + x1 * W3[c0 + 1];
#pragma unroll
  for (int off = 32; off > 0; off >>= 1) v += __shfl_down(v, off, 64);
  if (lane == 0) h3[w] = v;
}

// ---------------------------------------------------------------- final 1-wide propagation

static __global__ void prop3_kernel(const float* __restrict__ h3,
                                    const int* __restrict__ start, const int* __restrict__ blkOff,
                                    const int* __restrict__ cnt,
                                    const long long* __restrict__ edges,
                                    const float* __restrict__ dis, const float* __restrict__ b3,
                                    float* __restrict__ out, int N) {
  int i = blockIdx.x * blockDim.x + threadIdx.x;
  if (i >= N) return;
  float d = dis[i];
  float acc = d * h3[i];
  int s = start[i] + blkOff[i >> 10], n = cnt[i];
  for (int k = 0; k < n; ++k) {
    long long ev = edges[s + k];
    int src = (int)(unsigned int)(ev & 0xffffffffLL);
    float wt = __int_as_float((int)(ev >> 32));
    acc = fmaf(wt, h3[src], acc);
  }
  out[i] = acc * d + b3[0];
}

// ---------------------------------------------------------------- launch

extern "C" void kernel_launch(void* const* d_in, const int* in_sizes, int n_in,
                              void* d_out, int out_size, void* d_ws, size_t ws_size,
                              hipStream_t stream) {
  const float* x    = (const float*)d_in[0];
  const int*   ei   = (const int*)d_in[1];
  const float* ew   = (const float*)d_in[2];
  const float* W1   = (const float*)d_in[3];
  const float* b1   = (const float*)d_in[4];
  const float* W2   = (const float*)d_in[5];
  const float* b2   = (const float*)d_in[6];
  const float* W3   = (const float*)d_in[7];
  const float* b3   = (const float*)d_in[8];
  const float* Wres = (const float*)d_in[9];
  const float* g1   = (const float*)d_in[10];
  const float* be1  = (const float*)d_in[11];
  const float* m1   = (const float*)d_in[12];
  const float* v1   = (const float*)d_in[13];
  const float* g2   = (const float*)d_in[14];
  const float* be2  = (const float*)d_in[15];
  const float* m2   = (const float*)d_in[16];
  const float* v2   = (const float*)d_in[17];

  int Hh = in_sizes[4];            // 128
  int V  = in_sizes[3] / Hh;       // 256
  int N  = in_sizes[0] / V;        // 100000
  int E  = in_sizes[2];            // 1600000
  const int* row = ei;
  const int* col = ei + E;

  int Mp = ((N + 127) / 128) * 128;

  char* p = (char*)d_ws;
  auto alloc = [&](size_t bytes) -> char* {
    char* r = p;
    p += (bytes + 255) & ~(size_t)255;
    return r;
  };
  unsigned int* packed = (unsigned int*)alloc((size_t)N * 4);
  float* dis    = (float*)alloc((size_t)N * 4);
  int*   cnt    = (int*)  alloc((size_t)N * 4);
  int*   startA = (int*)  alloc((size_t)N * 4);
  int*   blkSum = (int*)  alloc(256 * 4);
  int*   blkOff = (int*)  alloc(256 * 4);
  unsigned short* rank = (unsigned short*)alloc((size_t)E * 2);
  long long* edges = (long long*)alloc((size_t)E * 8);
  float* h3     = (float*)alloc((size_t)N * 4);
  unsigned short* BT1 = (unsigned short*)alloc((size_t)256 * 256 * 2);
  unsigned short* BT2 = (unsigned short*)alloc((size_t)128 * 128 * 2);
  unsigned short* bufG  = (unsigned short*)alloc((size_t)Mp * 128 * 2);  // h0, then h1W2 (bf16)
  unsigned short* bufH1 = (unsigned short*)alloc((size_t)Mp * 128 * 2);  // h1 bf16
  unsigned short* bufRes = (unsigned short*)alloc((size_t)Mp * 128 * 2); // x@Wres bf16
  (void)ws_size; (void)n_in; (void)out_size;

  int TB = 256;
  hipMemsetAsync(packed, 0, (size_t)N * 4, stream);
  cast_weights<<<(256 * 256 + 128 * 128 + TB - 1) / TB, TB, 0, stream>>>(W1, Wres, W2, BT1, BT2);

  // fused: hist (blocks [0,hB)) THEN gemm1 (blocks [hB,hB+gB)) — short role first
  int gB = Mp / 64;
  int hB = (E + TB - 1) / TB;
  fused_hist_gemm1<<<hB + gB, TB, 0, stream>>>(x, BT1, bufG, bufRes, N,
                                               col, ew, packed, rank, E, hB);

  int nb = (N + SCAN_B * SCAN_I - 1) / (SCAN_B * SCAN_I);
  scanA<<<nb, SCAN_B, 0, stream>>>(packed, dis, cnt, startA, blkSum, N);
  scanB<<<1, 256, 0, stream>>>(blkSum, blkOff, nb);
  place_kernel<<<(E + TB - 1) / TB, TB, 0, stream>>>(row, col, ew, dis, startA, blkOff,
                                                     rank, edges, E);

  // prop1: h1 = relu(bn1(agg(h0) + b1)) -> bufH1 (bf16)
  int propBlocks = (int)(((size_t)N * 64 + TB - 1) / TB);
  prop128_bf16out<<<propBlocks, TB, 0, stream>>>((const unsigned int*)bufG, startA, blkOff, cnt,
                                                 edges, dis, b1, g1, be1, m1, v1,
                                                 (unsigned int*)bufH1, N);

  // GEMM2: h1 @ W2 -> bufG (bf16, reused)
  gemm2_mfma<<<Mp / 128, 256, 0, stream>>>(bufH1, BT2, bufG);

  // prop2 + fused W3: h3 = relu(bn2(agg(h1W2) + b2 + res)) . W3
  prop128_w3out<<<propBlocks, TB, 0, stream>>>((const unsigned int*)bufG, startA, blkOff, cnt,
                                               edges, dis, b2, g2, be2, m2, v2,
                                               (const unsigned int*)bufRes, W3, h3, N);

  // out = agg(h3) + b3
  prop3_kernel<<<(N + TB - 1) / TB, TB, 0, stream>>>(h3, startA, blkOff, cnt, edges,
                                                     dis, b3, (float*)d_out, N);
}

// Round 14
// 497.685 us; speedup vs baseline: 1.0304x; 1.0190x over previous
//
#include <hip/hip_runtime.h>
#include <hip/hip_bf16.h>

#define BN_EPS 1e-5f

using short8 = __attribute__((ext_vector_type(8))) short;
using f32x4  = __attribute__((ext_vector_type(4))) float;

// 32-bit packed histogram: cnt in [31:25], fixed-point ew-sum (2^-18) in [24:0].
#define FIX_SCALE 262144.0f
#define FIX_MASK  0x01ffffffu
#define CNT_ONE   (1u << 25)

static __device__ __forceinline__ unsigned short f2bf(float f) {
  unsigned int u = __float_as_uint(f);
  unsigned int r = (u + 0x7fffu + ((u >> 16) & 1u)) >> 16;
  return (unsigned short)r;
}

// ------------------------------------------------- weight cast (bf16, n-major)

static __global__ void cast_weights(const float* __restrict__ W1, const float* __restrict__ Wres,
                                    const float* __restrict__ W2,
                                    unsigned short* __restrict__ BT1,
                                    unsigned short* __restrict__ BT2) {
  int i = blockIdx.x * blockDim.x + threadIdx.x;
  if (i < 256 * 256) {
    int n = i >> 8, k = i & 255;
    float v = (n < 128) ? W1[k * 128 + n] : Wres[k * 128 + (n - 128)];
    BT1[i] = f2bf(v);
  } else if (i < 256 * 256 + 128 * 128) {
    int j = i - 256 * 256;
    int n = j >> 7, k = j & 127;
    BT2[j] = f2bf(W2[k * 128 + n]);
  }
}

// ---------------------------------------------------------------- fused GEMM1 + hist
// SAME-BLOCK fusion (R13 lesson: any block-level role split serializes —
// either role starves the block-slot window). Grid = gB; every block:
//   phase 1: its 1024-edge hist slice — 4 independent returning atomics/thread
//            (coalesced col/ew reads, e = b*1024 + j*256 + t);
//   phase 2: its R11 LDS-staged MFMA gemm tile (register-prefetch pipeline).
// All ~1563 blocks are co-resident (~5/CU at VGPR 100); each wave waits only
// for its OWN 4 atomics, so gemm compute of already-served waves runs in the
// shadow of the global atomic drain (~80 us) instead of after it.

static __global__ __launch_bounds__(256)
void fused_gemm1_hist(const float* __restrict__ A, const unsigned short* __restrict__ BT,
                      unsigned short* __restrict__ C0, unsigned short* __restrict__ C1, int M,
                      const int* __restrict__ col, const float* __restrict__ ew,
                      unsigned int* __restrict__ packed,
                      unsigned short* __restrict__ rank, int E) {
  __shared__ unsigned short As[64 * 40];
  __shared__ unsigned short Bs[256 * 40];

  int t = threadIdx.x;

  // ---------------- phase 1: hist slice
  {
    int ebase = blockIdx.x * 1024 + t;
#pragma unroll
    for (int j = 0; j < 4; ++j) {
      int e = ebase + j * 256;
      if (e < E) {
        int c = col[e];
        unsigned int fx = (unsigned int)(ew[e] * FIX_SCALE + 0.5f);
        unsigned int old = atomicAdd(&packed[c], CNT_ONE | fx);
        rank[e] = (unsigned short)(old >> 25);
      }
    }
  }

  // ---------------- phase 2: gemm tile (R11)
  int wv = t >> 6, lane = t & 63;
  int quad = lane >> 4, l15 = lane & 15;
  int m0 = blockIdx.x * 64;

  f32x4 acc[4][4];
#pragma unroll
  for (int i = 0; i < 4; ++i)
#pragma unroll
    for (int j = 0; j < 4; ++j) acc[i][j] = (f32x4){0.f, 0.f, 0.f, 0.f};

  int ar = t >> 2;
  int ac = (t & 3) * 8;
  bool avalid = (m0 + ar) < M;
  const float* Arow = A + (size_t)(m0 + ar) * 256 + ac;
  const unsigned short* Brow = BT + (size_t)t * 256;

  float4 a0 = make_float4(0.f, 0.f, 0.f, 0.f), a1 = a0;
  if (avalid) {
    a0 = *(const float4*)(Arow + 0);
    a1 = *(const float4*)(Arow + 4);
  }
  short8 b0 = *(const short8*)(Brow + 0);
  short8 b1 = *(const short8*)(Brow + 8);
  short8 b2 = *(const short8*)(Brow + 16);
  short8 b3 = *(const short8*)(Brow + 24);

  for (int k0 = 0; k0 < 256; k0 += 32) {
    short8 av;
    av[0] = (short)f2bf(a0.x); av[1] = (short)f2bf(a0.y);
    av[2] = (short)f2bf(a0.z); av[3] = (short)f2bf(a0.w);
    av[4] = (short)f2bf(a1.x); av[5] = (short)f2bf(a1.y);
    av[6] = (short)f2bf(a1.z); av[7] = (short)f2bf(a1.w);
    *(short8*)&As[ar * 40 + ac] = av;
    *(short8*)&Bs[t * 40 + 0]  = b0;
    *(short8*)&Bs[t * 40 + 8]  = b1;
    *(short8*)&Bs[t * 40 + 16] = b2;
    *(short8*)&Bs[t * 40 + 24] = b3;
    __syncthreads();

    if (k0 + 32 < 256) {
      int kn = k0 + 32;
      if (avalid) {
        a0 = *(const float4*)(Arow + kn);
        a1 = *(const float4*)(Arow + kn + 4);
      }
      b0 = *(const short8*)(Brow + kn);
      b1 = *(const short8*)(Brow + kn + 8);
      b2 = *(const short8*)(Brow + kn + 16);
      b3 = *(const short8*)(Brow + kn + 24);
    }

    short8 af[4], bf[4];
#pragma unroll
    for (int mt = 0; mt < 4; ++mt)
      af[mt] = *(const short8*)&As[(mt * 16 + l15) * 40 + quad * 8];
#pragma unroll
    for (int nt = 0; nt < 4; ++nt)
      bf[nt] = *(const short8*)&Bs[(wv * 64 + nt * 16 + l15) * 40 + quad * 8];
#pragma unroll
    for (int mt = 0; mt < 4; ++mt)
#pragma unroll
      for (int nt = 0; nt < 4; ++nt)
        acc[mt][nt] = __builtin_amdgcn_mfma_f32_16x16x32_bf16(af[mt], bf[nt], acc[mt][nt], 0, 0, 0);
    __syncthreads();
  }

  int nbase = wv * 64;
#pragma unroll
  for (int mt = 0; mt < 4; ++mt) {
#pragma unroll
    for (int nt = 0; nt < 4; ++nt) {
      int n = nbase + nt * 16 + l15;
#pragma unroll
      for (int reg = 0; reg < 4; ++reg) {
        size_t m = (size_t)(m0 + mt * 16 + quad * 4 + reg);
        if (nbase < 128) C0[m * 128 + n] = f2bf(acc[mt][nt][reg]);
        else             C1[m * 128 + (n - 128)] = f2bf(acc[mt][nt][reg]);
      }
    }
  }
}

// ---------------------------------------------------------------- scan (unpack folded in)

#define SCAN_B 256
#define SCAN_I 4
static __global__ void scanA(const unsigned int* __restrict__ packed,
                             float* __restrict__ dis, int* __restrict__ cnt,
                             int* __restrict__ start, int* __restrict__ blkSum, int N) {
  __shared__ int sh[SCAN_B];
  int t = threadIdx.x;
  int base = blockIdx.x * SCAN_B * SCAN_I + t * SCAN_I;
  int v[SCAN_I];
  int tot = 0;
#pragma unroll
  for (int j = 0; j < SCAN_I; ++j) {
    if (base + j < N) {
      unsigned int pv = packed[base + j];
      v[j] = (int)(pv >> 25);
      cnt[base + j] = v[j];
      float deg = 1.0f + (float)(pv & FIX_MASK) * (1.0f / FIX_SCALE);
      dis[base + j] = rsqrtf(deg);
    } else v[j] = 0;
    tot += v[j];
  }
  sh[t] = tot;
  __syncthreads();
  int self = tot;
  for (int off = 1; off < SCAN_B; off <<= 1) {
    int add = (t >= off) ? sh[t - off] : 0;
    __syncthreads();
    sh[t] += add;
    __syncthreads();
  }
  int excl = sh[t] - self;
  if (t == SCAN_B - 1) blkSum[blockIdx.x] = sh[t];
  int run = excl;
#pragma unroll
  for (int j = 0; j < SCAN_I; ++j) {
    if (base + j < N) start[base + j] = run;
    run += v[j];
  }
}

static __global__ void scanB(const int* __restrict__ blkSum, int* __restrict__ blkOff, int nb) {
  __shared__ int sh[256];
  int t = threadIdx.x;
  int v = (t < nb) ? blkSum[t] : 0;
  sh[t] = v;
  __syncthreads();
  for (int off = 1; off < 256; off <<= 1) {
    int add = (t >= off) ? sh[t - off] : 0;
    __syncthreads();
    sh[t] += add;
    __syncthreads();
  }
  if (t < nb) blkOff[t] = sh[t] - v;
}

static __global__ void scanC(int* start, const int* __restrict__ blkOff, int N) {
  int i = blockIdx.x * blockDim.x + threadIdx.x;
  if (i < N) start[i] += blkOff[i / (SCAN_B * SCAN_I)];
}

// atomic-free placement: pos = start[col] + rank. edges[pos] = (src, dis[src]*ew)
static __global__ void place_kernel(const int* __restrict__ row, const int* __restrict__ col,
                                    const float* __restrict__ ew, const float* __restrict__ dis,
                                    const int* __restrict__ start,
                                    const unsigned short* __restrict__ rank,
                                    long long* __restrict__ edges, int E) {
  int e = blockIdx.x * blockDim.x + threadIdx.x;
  if (e < E) {
    int r = row[e], c = col[e];
    int pos = start[c] + (int)rank[e];
    float nrm = dis[r] * ew[e];
    long long v = ((long long)__float_as_int(nrm) << 32) | (unsigned int)r;
    __builtin_nontemporal_store(v, &edges[pos]);
  }
}

// ---------------------------------------------------------------- GEMM2 (LDS-staged MFMA)

static __global__ __launch_bounds__(256)
void gemm2_mfma(const unsigned short* __restrict__ A, const unsigned short* __restrict__ BT,
                unsigned short* __restrict__ C) {
  __shared__ unsigned short As[128 * 40];
  __shared__ unsigned short Bs[128 * 40];
  int t = threadIdx.x;
  int wv = t >> 6, lane = t & 63;
  int quad = lane >> 4, l15 = lane & 15;
  int m0 = blockIdx.x * 128;

  f32x4 acc[4][4];
#pragma unroll
  for (int i = 0; i < 4; ++i)
#pragma unroll
    for (int j = 0; j < 4; ++j) acc[i][j] = (f32x4){0.f, 0.f, 0.f, 0.f};

  int sr = t >> 1, sc = (t & 1) * 16;

  for (int k0 = 0; k0 < 128; k0 += 32) {
    short8 a0 = *(const short8*)(A + (size_t)(m0 + sr) * 128 + k0 + sc);
    short8 a1 = *(const short8*)(A + (size_t)(m0 + sr) * 128 + k0 + sc + 8);
    *(short8*)&As[sr * 40 + sc]     = a0;
    *(short8*)&As[sr * 40 + sc + 8] = a1;
    short8 b0 = *(const short8*)(BT + (size_t)sr * 128 + k0 + sc);
    short8 b1 = *(const short8*)(BT + (size_t)sr * 128 + k0 + sc + 8);
    *(short8*)&Bs[sr * 40 + sc]     = b0;
    *(short8*)&Bs[sr * 40 + sc + 8] = b1;
    __syncthreads();

    int mb = (wv >> 1) * 64, nb = (wv & 1) * 64;
    short8 af[4], bf[4];
#pragma unroll
    for (int mt = 0; mt < 4; ++mt)
      af[mt] = *(const short8*)&As[(mb + mt * 16 + l15) * 40 + quad * 8];
#pragma unroll
    for (int nt = 0; nt < 4; ++nt)
      bf[nt] = *(const short8*)&Bs[(nb + nt * 16 + l15) * 40 + quad * 8];
#pragma unroll
    for (int mt = 0; mt < 4; ++mt)
#pragma unroll
      for (int nt = 0; nt < 4; ++nt)
        acc[mt][nt] = __builtin_amdgcn_mfma_f32_16x16x32_bf16(af[mt], bf[nt], acc[mt][nt], 0, 0, 0);
    __syncthreads();
  }

  int mb = (wv >> 1) * 64, nb = (wv & 1) * 64;
#pragma unroll
  for (int mt = 0; mt < 4; ++mt)
#pragma unroll
    for (int nt = 0; nt < 4; ++nt) {
      int n = nb + nt * 16 + l15;
#pragma unroll
      for (int reg = 0; reg < 4; ++reg) {
        size_t m = (size_t)(m0 + mb + mt * 16 + quad * 4 + reg);
        C[m * 128 + n] = f2bf(acc[mt][nt][reg]);
      }
    }
}

// ---------------------------------------------------------------- propagation core (R11 form)
// One wave per destination node; lane holds 2 channels (one bf16x2 word).
// Uniform-index __shfl broadcasts (v_readlane) + 8 independent 4 B gathers/group.

#define PROP_GATHER_BODY                                                        \
  int c0 = lane * 2;                                                            \
  float d = dis[w];                                                             \
  float acc0, acc1;                                                             \
  {                                                                             \
    unsigned int u = Hsrc[(size_t)w * 64 + lane];                               \
    acc0 = d * __uint_as_float(u << 16);                                        \
    acc1 = d * __uint_as_float(u & 0xffff0000u);                                \
  }                                                                             \
  int s = start[w], n = cnt[w];                                                 \
  int k = 0;                                                                    \
  while (k < n) {                                                               \
    int chunk = min(n - k, 64);                                                 \
    int idx = 0;                                                                \
    float wt = 0.f;                                                             \
    if (lane < chunk) {                                                         \
      long long ev = edges[s + k + lane];                                       \
      idx = (int)(unsigned int)(ev & 0xffffffffLL);                             \
      wt  = __int_as_float((int)(ev >> 32));                                    \
    }                                                                           \
    for (int j = 0; j < chunk; j += 8) {                                        \
      int   i0 = __shfl(idx, j + 0, 64), i1 = __shfl(idx, j + 1, 64);           \
      int   i2 = __shfl(idx, j + 2, 64), i3 = __shfl(idx, j + 3, 64);           \
      int   i4 = __shfl(idx, j + 4, 64), i5 = __shfl(idx, j + 5, 64);           \
      int   i6 = __shfl(idx, j + 6, 64), i7 = __shfl(idx, j + 7, 64);           \
      float w0 = __shfl(wt, j + 0, 64), w1 = __shfl(wt, j + 1, 64);             \
      float w2 = __shfl(wt, j + 2, 64), w3 = __shfl(wt, j + 3, 64);             \
      float w4 = __shfl(wt, j + 4, 64), w5 = __shfl(wt, j + 5, 64);             \
      float w6 = __shfl(wt, j + 6, 64), w7 = __shfl(wt, j + 7, 64);             \
      unsigned int u0 = Hsrc[(size_t)i0 * 64 + lane];                           \
      unsigned int u1 = Hsrc[(size_t)i1 * 64 + lane];                           \
      unsigned int u2 = Hsrc[(size_t)i2 * 64 + lane];                           \
      unsigned int u3 = Hsrc[(size_t)i3 * 64 + lane];                           \
      unsigned int u4 = Hsrc[(size_t)i4 * 64 + lane];                           \
      unsigned int u5 = Hsrc[(size_t)i5 * 64 + lane];                           \
      unsigned int u6 = Hsrc[(size_t)i6 * 64 + lane];                           \
      unsigned int u7 = Hsrc[(size_t)i7 * 64 + lane];                           \
      acc0 = fmaf(w0, __uint_as_float(u0 << 16), acc0);                         \
      acc1 = fmaf(w0, __uint_as_float(u0 & 0xffff0000u), acc1);                 \
      acc0 = fmaf(w1, __uint_as_float(u1 << 16), acc0);                         \
      acc1 = fmaf(w1, __uint_as_float(u1 & 0xffff0000u), acc1);                 \
      acc0 = fmaf(w2, __uint_as_float(u2 << 16), acc0);                         \
      acc1 = fmaf(w2, __uint_as_float(u2 & 0xffff0000u), acc1);                 \
      acc0 = fmaf(w3, __uint_as_float(u3 << 16), acc0);                         \
      acc1 = fmaf(w3, __uint_as_float(u3 & 0xffff0000u), acc1);                 \
      acc0 = fmaf(w4, __uint_as_float(u4 << 16), acc0);                         \
      acc1 = fmaf(w4, __uint_as_float(u4 & 0xffff0000u), acc1);                 \
      acc0 = fmaf(w5, __uint_as_float(u5 << 16), acc0);                         \
      acc1 = fmaf(w5, __uint_as_float(u5 & 0xffff0000u), acc1);                 \
      acc0 = fmaf(w6, __uint_as_float(u6 << 16), acc0);                         \
      acc1 = fmaf(w6, __uint_as_float(u6 & 0xffff0000u), acc1);                 \
      acc0 = fmaf(w7, __uint_as_float(u7 << 16), acc0);                         \
      acc1 = fmaf(w7, __uint_as_float(u7 & 0xffff0000u), acc1);                 \
    }                                                                           \
    k += chunk;                                                                 \
  }                                                                             \
  acc0 *= d;                                                                    \
  acc1 *= d;

// prop1: h1 = relu(bn1(agg + b1)) -> bf16 packed output
static __global__ __launch_bounds__(256)
void prop128_bf16out(const unsigned int* __restrict__ Hsrc,
                     const int* __restrict__ start, const int* __restrict__ cnt,
                     const long long* __restrict__ edges,
                     const float* __restrict__ dis,
                     const float* __restrict__ bvec,
                     const float* __restrict__ g, const float* __restrict__ be,
                     const float* __restrict__ mean, const float* __restrict__ var,
                     unsigned int* __restrict__ Outb, int N) {
  int w = (int)((blockIdx.x * blockDim.x + threadIdx.x) >> 6);
  int lane = threadIdx.x & 63;
  if (w >= N) return;
  PROP_GATHER_BODY
  float x0 = acc0 + bvec[c0];
  float x1 = acc1 + bvec[c0 + 1];
  float s0 = g[c0] * rsqrtf(var[c0] + BN_EPS);
  float s1 = g[c0 + 1] * rsqrtf(var[c0 + 1] + BN_EPS);
  x0 = fmaxf((x0 - mean[c0]) * s0 + be[c0], 0.f);
  x1 = fmaxf((x1 - mean[c0 + 1]) * s1 + be[c0 + 1], 0.f);
  unsigned int packed = (unsigned int)f2bf(x0) | ((unsigned int)f2bf(x1) << 16);
  Outb[(size_t)w * 64 + lane] = packed;
}

// prop2: h2 = relu(bn2(agg + b2 + res)); fused h3[w] = dot(h2_row, W3).
static __global__ __launch_bounds__(256)
void prop128_w3out(const unsigned int* __restrict__ Hsrc,
                   const int* __restrict__ start, const int* __restrict__ cnt,
                   const long long* __restrict__ edges,
                   const float* __restrict__ dis,
                   const float* __restrict__ bvec,
                   const float* __restrict__ g, const float* __restrict__ be,
                   const float* __restrict__ mean, const float* __restrict__ var,
                   const unsigned int* __restrict__ resb, const float* __restrict__ W3,
                   float* __restrict__ h3, int N) {
  int w = (int)((blockIdx.x * blockDim.x + threadIdx.x) >> 6);
  int lane = threadIdx.x & 63;
  if (w >= N) return;
  PROP_GATHER_BODY
  unsigned int ru = resb[(size_t)w * 64 + lane];
  float x0 = acc0 + bvec[c0]     + __uint_as_float(ru << 16);
  float x1 = acc1 + bvec[c0 + 1] + __uint_as_float(ru & 0xffff0000u);
  float s0 = g[c0] * rsqrtf(var[c0] + BN_EPS);
  float s1 = g[c0 + 1] * rsqrtf(var[c0 + 1] + BN_EPS);
  x0 = fmaxf((x0 - mean[c0]) * s0 + be[c0], 0.f);
  x1 = fmaxf((x1 - mean[c0 + 1]) * s1 + be[c0 + 1], 0.f);
  float v = x0 * W3[c0] + x1 * W3[c0 + 1];
#pragma unroll
  for (int off = 32; off > 0; off >>= 1) v += __shfl_down(v, off, 64);
  if (lane == 0) h3[w] = v;
}

// ---------------------------------------------------------------- final 1-wide propagation

static __global__ void prop3_kernel(const float* __restrict__ h3,
                                    const int* __restrict__ start, const int* __restrict__ cnt,
                                    const long long* __restrict__ edges,
                                    const float* __restrict__ dis, const float* __restrict__ b3,
                                    float* __restrict__ out, int N) {
  int i = blockIdx.x * blockDim.x + threadIdx.x;
  if (i >= N) return;
  float d = dis[i];
  float acc = d * h3[i];
  int s = start[i], n = cnt[i];
  for (int k = 0; k < n; ++k) {
    long long ev = edges[s + k];
    int src = (int)(unsigned int)(ev & 0xffffffffLL);
    float wt = __int_as_float((int)(ev >> 32));
    acc = fmaf(wt, h3[src], acc);
  }
  out[i] = acc * d + b3[0];
}

// ---------------------------------------------------------------- launch

extern "C" void kernel_launch(void* const* d_in, const int* in_sizes, int n_in,
                              void* d_out, int out_size, void* d_ws, size_t ws_size,
                              hipStream_t stream) {
  const float* x    = (const float*)d_in[0];
  const int*   ei   = (const int*)d_in[1];
  const float* ew   = (const float*)d_in[2];
  const float* W1   = (const float*)d_in[3];
  const float* b1   = (const float*)d_in[4];
  const float* W2   = (const float*)d_in[5];
  const float* b2   = (const float*)d_in[6];
  const float* W3   = (const float*)d_in[7];
  const float* b3   = (const float*)d_in[8];
  const float* Wres = (const float*)d_in[9];
  const float* g1   = (const float*)d_in[10];
  const float* be1  = (const float*)d_in[11];
  const float* m1   = (const float*)d_in[12];
  const float* v1   = (const float*)d_in[13];
  const float* g2   = (const float*)d_in[14];
  const float* be2  = (const float*)d_in[15];
  const float* m2   = (const float*)d_in[16];
  const float* v2   = (const float*)d_in[17];

  int Hh = in_sizes[4];            // 128
  int V  = in_sizes[3] / Hh;       // 256
  int N  = in_sizes[0] / V;        // 100000
  int E  = in_sizes[2];            // 1600000
  const int* row = ei;
  const int* col = ei + E;

  int Mp = ((N + 127) / 128) * 128;

  char* p = (char*)d_ws;
  auto alloc = [&](size_t bytes) -> char* {
    char* r = p;
    p += (bytes + 255) & ~(size_t)255;
    return r;
  };
  unsigned int* packed = (unsigned int*)alloc((size_t)N * 4);
  float* dis    = (float*)alloc((size_t)N * 4);
  int*   cnt    = (int*)  alloc((size_t)N * 4);
  int*   startA = (int*)  alloc((size_t)N * 4);
  int*   blkSum = (int*)  alloc(256 * 4);
  int*   blkOff = (int*)  alloc(256 * 4);
  unsigned short* rank = (unsigned short*)alloc((size_t)E * 2);
  long long* edges = (long long*)alloc((size_t)E * 8);
  float* h3     = (float*)alloc((size_t)N * 4);
  unsigned short* BT1 = (unsigned short*)alloc((size_t)256 * 256 * 2);
  unsigned short* BT2 = (unsigned short*)alloc((size_t)128 * 128 * 2);
  unsigned short* bufG  = (unsigned short*)alloc((size_t)Mp * 128 * 2);  // h0, then h1W2 (bf16)
  unsigned short* bufH1 = (unsigned short*)alloc((size_t)Mp * 128 * 2);  // h1 bf16
  unsigned short* bufRes = (unsigned short*)alloc((size_t)Mp * 128 * 2); // x@Wres bf16
  (void)ws_size; (void)n_in; (void)out_size;

  int TB = 256;
  hipMemsetAsync(packed, 0, (size_t)N * 4, stream);
  cast_weights<<<(256 * 256 + 128 * 128 + TB - 1) / TB, TB, 0, stream>>>(W1, Wres, W2, BT1, BT2);

  // fused: every block = 1024-edge hist slice + one gemm1 tile.
  // gB*1024 = 1,600,512 >= E covers all edges.
  int gB = Mp / 64;
  fused_gemm1_hist<<<gB, TB, 0, stream>>>(x, BT1, bufG, bufRes, N,
                                          col, ew, packed, rank, E);

  int nb = (N + SCAN_B * SCAN_I - 1) / (SCAN_B * SCAN_I);
  scanA<<<nb, SCAN_B, 0, stream>>>(packed, dis, cnt, startA, blkSum, N);
  scanB<<<1, 256, 0, stream>>>(blkSum, blkOff, nb);
  scanC<<<(N + TB - 1) / TB, TB, 0, stream>>>(startA, blkOff, N);
  place_kernel<<<(E + TB - 1) / TB, TB, 0, stream>>>(row, col, ew, dis, startA,
                                                     rank, edges, E);

  // prop1: h1 = relu(bn1(agg(h0) + b1)) -> bufH1 (bf16)
  int propBlocks = (int)(((size_t)N * 64 + TB - 1) / TB);
  prop128_bf16out<<<propBlocks, TB, 0, stream>>>((const unsigned int*)bufG, startA, cnt,
                                                 edges, dis, b1, g1, be1, m1, v1,
                                                 (unsigned int*)bufH1, N);

  // GEMM2: h1 @ W2 -> bufG (bf16, reused)
  gemm2_mfma<<<Mp / 128, 256, 0, stream>>>(bufH1, BT2, bufG);

  // prop2 + fused W3: h3 = relu(bn2(agg(h1W2) + b2 + res)) . W3
  prop128_w3out<<<propBlocks, TB, 0, stream>>>((const unsigned int*)bufG, startA, cnt,
                                               edges, dis, b2, g2, be2, m2, v2,
                                               (const unsigned int*)bufRes, W3, h3, N);

  // out = agg(h3) + b3
  prop3_kernel<<<(N + TB - 1) / TB, TB, 0, stream>>>(h3, startA, cnt, edges,
                                                     dis, b3, (float*)d_out, N);
}